// Round 1
// baseline (49.051 us; speedup 1.0000x reference)
//
#include <hip/hip_runtime.h>
#include <math.h>

// Biquad lowpass over [B, T] f32, T = 262144.
// Overlap-and-discard: poles |z| = sqrt(a2) ~= 0.6425 -> 64-sample warm-up
// reduces init-state error to ~5e-13 (threshold 2e-2). Each thread owns one
// 128-sample chunk, runs recurrence from chunk_start-64 with zero state.
constexpr int T_LEN = 262144;
constexpr int CHUNK = 128;
constexpr int WARM  = 64;
constexpr int CPR   = T_LEN / CHUNK; // 2048 chunks per row

__global__ __launch_bounds__(256, 2) void lowpass_kernel(
    const float* __restrict__ x, float* __restrict__ out,
    float b0, float b1, float b2, float a1, float a2)
{
    int g = blockIdx.x * 256 + threadIdx.x;
    int row   = g >> 11;        // g / CPR
    int chunk = g & (CPR - 1);  // g % CPR
    const float* __restrict__ xr = x   + (size_t)row * T_LEN;
    float*       __restrict__ yr = out + (size_t)row * T_LEN;

    const int cstart = chunk * CHUNK;
    const int s = cstart - WARM;   // warm-up start (-64 only for chunk 0)

    float x1 = 0.f, x2 = 0.f;
    if (s >= 2) { x1 = xr[s - 1]; x2 = xr[s - 2]; }
    float y1 = 0.f, y2 = 0.f;

    auto step = [&](float xc) -> float {
        float u = b0 * xc + b1 * x1 + b2 * x2;
        float y = u - a1 * y1 - a2 * y2;
        x2 = x1; x1 = xc;
        y2 = y1; y1 = y;
        return y;
    };

    if (s >= 0) {
        // warm-up: compute recurrence, discard outputs
        #pragma unroll 4
        for (int t = s; t < cstart; t += 4) {
            float4 xv = *reinterpret_cast<const float4*>(xr + t);
            step(xv.x); step(xv.y); step(xv.z); step(xv.w);
        }
    }
    // chunk 0 (s < 0): no warm-up, true zero initial state (matches reference)

    #pragma unroll 4
    for (int t = cstart; t < cstart + CHUNK; t += 4) {
        float4 xv = *reinterpret_cast<const float4*>(xr + t);
        float4 ov;
        ov.x = fminf(fmaxf(step(xv.x), -1.f), 1.f);
        ov.y = fminf(fmaxf(step(xv.y), -1.f), 1.f);
        ov.z = fminf(fmaxf(step(xv.z), -1.f), 1.f);
        ov.w = fminf(fmaxf(step(xv.w), -1.f), 1.f);
        *reinterpret_cast<float4*>(yr + t) = ov;
    }
}

extern "C" void kernel_launch(void* const* d_in, const int* in_sizes, int n_in,
                              void* d_out, int out_size, void* d_ws, size_t ws_size,
                              hipStream_t stream) {
    const float* x = (const float*)d_in[0];
    float* out = (float*)d_out;
    const int rows = in_sizes[0] / T_LEN;   // 64

    // torchaudio lowpass_biquad coefficients (double, then cast to f32 — same
    // as the numpy reference path)
    const double SR = 22050.0, CUT = 0.4 * SR, Q = 0.707;
    double w0 = 2.0 * M_PI * CUT / SR;
    double alpha = sin(w0) / (2.0 * Q);
    double cosw = cos(w0);
    double a0d = 1.0 + alpha;
    float b0 = (float)((1.0 - cosw) / 2.0 / a0d);
    float b1 = (float)((1.0 - cosw) / a0d);
    float b2 = b0;
    float a1 = (float)(-2.0 * cosw / a0d);
    float a2 = (float)((1.0 - alpha) / a0d);

    int total_threads = rows * CPR;         // 131072
    int blocks = total_threads / 256;       // 512
    lowpass_kernel<<<blocks, 256, 0, stream>>>(x, out, b0, b1, b2, a1, a2);
}

// Round 2
// 29.028 us; speedup vs baseline: 1.6898x; 1.6898x over previous
//
#include <hip/hip_runtime.h>
#include <math.h>

// Biquad lowpass over [B, T] f32, T = 262144.
// Overlap-and-discard with LDS-staged coalesced I/O:
//  - block of 256 threads owns a contiguous 8192-float segment (32/thread)
//  - stage [seg-64, seg+8192) via coalesced float4 loads into swizzled LDS
//    (s(i) = i + i/32: per-step lane reads hit banks (i+t)%32 -> 2-way, free)
//  - each thread runs 64 warm-up + 32 output steps from LDS (poles |z|~0.6425,
//    64-step discard -> ~5e-13 state error vs 2e-2 threshold)
//  - outputs kept in 32 registers (fully unrolled, static idx), then staged
//    through LDS and stored as coalesced float4 (kills write amplification)
constexpr int T_LEN = 262144;
constexpr int CH    = 32;              // outputs per thread
constexpr int WARM  = 64;
constexpr int TPB   = 256;
constexpr int SEG   = TPB * CH;        // 8192 floats per block
constexpr int LTOT  = SEG + WARM;      // 8256 floats staged
constexpr int LSWZ  = LTOT + LTOT/32 + 4; // swizzled extent
constexpr int BPR   = T_LEN / SEG;     // 32 blocks per row

__device__ __forceinline__ int swz(int i) { return i + (i >> 5); }

__global__ __launch_bounds__(TPB, 4) void lowpass_kernel(
    const float* __restrict__ x, float* __restrict__ out,
    float b0, float b1, float b2, float a1, float a2)
{
    __shared__ float lds[LSWZ];
    const int tid = threadIdx.x;
    const size_t rbase = (size_t)(blockIdx.x / BPR) * T_LEN;
    const int blk  = blockIdx.x % BPR;       // BPR=32 -> compiler uses shifts
    const int seg0 = blk * SEG;              // row-local segment start
    const float* __restrict__ xr = x   + rbase;
    float*       __restrict__ yr = out + rbase;

    // ---- stage [seg0-WARM, seg0+SEG) coalesced; zeros before row start ----
    for (int m = tid; m < LTOT / 4; m += TPB) {
        const int idx  = 4 * m;              // local index in staged window
        const int gpos = seg0 - WARM + idx;  // row-local sample index
        float4 v = make_float4(0.f, 0.f, 0.f, 0.f);
        if (gpos >= 0) v = *reinterpret_cast<const float4*>(xr + gpos);
        const int sb = swz(idx);             // idx%4==0 -> 4 consecutive slots
        lds[sb + 0] = v.x; lds[sb + 1] = v.y;
        lds[sb + 2] = v.z; lds[sb + 3] = v.w;
    }
    __syncthreads();

    // ---- recurrence: 64 warm-up + 32 output steps ----
    // thread tid covers local window [32*tid, 32*tid + 96)
    float x1 = 0.f, x2 = 0.f, y1 = 0.f, y2 = 0.f;
    const int b = 33 * tid;                  // swz(32*tid)
    float o[CH];
    #pragma unroll
    for (int t = 0; t < WARM; ++t) {
        // swz(32*tid + t) = 33*tid + t + (t>>5)
        const float xc = lds[b + t + (t >> 5)];
        const float u  = fmaf(b0, xc, fmaf(b1, x1, b2 * x2));
        const float y  = fmaf(-a1, y1, fmaf(-a2, y2, u));
        x2 = x1; x1 = xc; y2 = y1; y1 = y;
    }
    #pragma unroll
    for (int t = 0; t < CH; ++t) {
        // swz(32*tid + 64 + t) = 66 + 33*tid + t   (t < 32)
        const float xc = lds[66 + b + t];
        const float u  = fmaf(b0, xc, fmaf(b1, x1, b2 * x2));
        const float y  = fmaf(-a1, y1, fmaf(-a2, y2, u));
        x2 = x1; x1 = xc; y2 = y1; y1 = y;
        o[t] = fminf(fmaxf(y, -1.f), 1.f);
    }
    __syncthreads();   // all input reads done before overwrite

    // ---- stage outputs back (same swizzled slots as their input samples) ----
    #pragma unroll
    for (int t = 0; t < CH; ++t) lds[66 + b + t] = o[t];
    __syncthreads();

    // ---- coalesced float4 store ----
    for (int m = tid; m < SEG / 4; m += TPB) {
        const int idx = WARM + 4 * m;        // local output index
        const int sb  = swz(idx);            // 4 consecutive slots
        float4 v = make_float4(lds[sb], lds[sb + 1], lds[sb + 2], lds[sb + 3]);
        *reinterpret_cast<float4*>(yr + seg0 + 4 * m) = v;
    }
}

extern "C" void kernel_launch(void* const* d_in, const int* in_sizes, int n_in,
                              void* d_out, int out_size, void* d_ws, size_t ws_size,
                              hipStream_t stream) {
    const float* x = (const float*)d_in[0];
    float* out = (float*)d_out;
    const int rows = in_sizes[0] / T_LEN;    // 64

    // torchaudio lowpass_biquad coefficients (double -> f32, matches reference)
    const double SR = 22050.0, CUT = 0.4 * SR, Q = 0.707;
    double w0 = 2.0 * M_PI * CUT / SR;
    double alpha = sin(w0) / (2.0 * Q);
    double cosw = cos(w0);
    double a0d = 1.0 + alpha;
    float b0 = (float)((1.0 - cosw) / 2.0 / a0d);
    float b1 = (float)((1.0 - cosw) / a0d);
    float b2 = b0;
    float a1 = (float)(-2.0 * cosw / a0d);
    float a2 = (float)((1.0 - alpha) / a0d);

    const int blocks = rows * BPR;           // 64 * 32 = 2048
    lowpass_kernel<<<blocks, TPB, 0, stream>>>(x, out, b0, b1, b2, a1, a2);
}